// Round 1
// baseline (21.610 us; speedup 1.0000x reference)
//
#include <hip/hip_runtime.h>
#include <cmath>

// NCE LM loss: only N*(K+1) dot products are needed, never the full logits.
// N = B*T = 2048, D = 1024, K = 20 (derived from in_sizes at launch).

__device__ __forceinline__ float log_sigmoid_f(float x) {
    // log(sigmoid(x)) = min(x,0) - log1p(exp(-|x|))   (stable, matches jax.nn.log_sigmoid)
    return fminf(x, 0.0f) - log1pf(expf(-fabsf(x)));
}

__global__ __launch_bounds__(256) void nce_rows_kernel(
    const float* __restrict__ hidden,     // (N, D)
    const int*   __restrict__ targets,    // (N,)
    const float* __restrict__ W,          // (V, D)
    const int*   __restrict__ noise_ids,  // (K,)
    float* __restrict__ partials,         // ws: [0..N) pos terms, [N..2N) neg row-sums
    int N, int K, float shift)            // shift = log(V) - log(K)
{
    __shared__ float4 shv[256];           // one hidden row: 1024 f32
    __shared__ float  spos[4], sneg[4];

    const int row  = blockIdx.x;
    const int tid  = threadIdx.x;
    const int wave = tid >> 6;
    const int lane = tid & 63;

    // Stage hidden row in LDS (256 threads x float4 = 1024 floats, coalesced).
    const float4* hv = reinterpret_cast<const float4*>(hidden + (size_t)row * 1024);
    shv[tid] = hv[tid];
    __syncthreads();

    const int tgt = targets[row];

    float pos = 0.0f, neg = 0.0f;
    // 21 dot products (id 0 = target row, ids 1..K = noise rows), round-robin over 4 waves.
    for (int id = wave; id <= K; id += 4) {
        const int wrow = (id == 0) ? tgt : noise_ids[id - 1];
        const float4* wv = reinterpret_cast<const float4*>(W + (size_t)wrow * 1024);
        float acc = 0.0f;
        #pragma unroll
        for (int j = 0; j < 4; ++j) {
            float4 a = shv[lane + 64 * j];   // LDS read
            float4 b = wv[lane + 64 * j];    // coalesced global_load_dwordx4
            acc = fmaf(a.x, b.x, acc);
            acc = fmaf(a.y, b.y, acc);
            acc = fmaf(a.z, b.z, acc);
            acc = fmaf(a.w, b.w, acc);
        }
        // 64-lane butterfly reduce
        #pragma unroll
        for (int off = 32; off > 0; off >>= 1)
            acc += __shfl_xor(acc, off, 64);
        if (lane == 0) {
            const float s = acc + shift;     // score - log_k - log_unif
            if (id == 0) pos += log_sigmoid_f(s);
            else         neg += log_sigmoid_f(-s);
        }
    }

    if (lane == 0) { spos[wave] = pos; sneg[wave] = neg; }
    __syncthreads();
    if (tid == 0) {
        partials[row]     = spos[0] + spos[1] + spos[2] + spos[3];
        partials[N + row] = sneg[0] + sneg[1] + sneg[2] + sneg[3];
    }
}

__global__ __launch_bounds__(256) void nce_finalize_kernel(
    const float* __restrict__ partials, float* __restrict__ out, int N, int K)
{
    __shared__ float sp[4], sn[4];
    const int tid  = threadIdx.x;
    const int wave = tid >> 6;
    const int lane = tid & 63;

    float p = 0.0f, n = 0.0f;
    for (int i = tid; i < N; i += 256) {
        p += partials[i];
        n += partials[N + i];
    }
    #pragma unroll
    for (int off = 32; off > 0; off >>= 1) {
        p += __shfl_xor(p, off, 64);
        n += __shfl_xor(n, off, 64);
    }
    if (lane == 0) { sp[wave] = p; sn[wave] = n; }
    __syncthreads();
    if (tid == 0) {
        const float P  = sp[0] + sp[1] + sp[2] + sp[3];
        const float Ng = sn[0] + sn[1] + sn[2] + sn[3];
        out[0] = -P / (float)N - Ng / ((float)N * (float)K);
    }
}

extern "C" void kernel_launch(void* const* d_in, const int* in_sizes, int n_in,
                              void* d_out, int out_size, void* d_ws, size_t ws_size,
                              hipStream_t stream) {
    const float* hidden    = (const float*)d_in[0];
    const int*   targets   = (const int*)d_in[1];
    const float* W         = (const float*)d_in[2];
    const int*   noise_ids = (const int*)d_in[3];

    const int N = in_sizes[1];             // B*T = 2048
    const int D = in_sizes[0] / N;         // 1024
    const int K = in_sizes[3];             // 20
    const int V = in_sizes[2] / D;         // 50257
    (void)D;

    const float shift = logf((float)V) - logf((float)K);

    float* partials = (float*)d_ws;        // 2*N floats, all slots overwritten each call

    nce_rows_kernel<<<N, 256, 0, stream>>>(hidden, targets, W, noise_ids,
                                           partials, N, K, shift);
    nce_finalize_kernel<<<1, 256, 0, stream>>>(partials, (float*)d_out, N, K);
}